// Round 16
// baseline (790.077 us; speedup 1.0000x reference)
//
#include <hip/hip_runtime.h>
#include <hip/hip_bf16.h>

typedef short bf16x8 __attribute__((ext_vector_type(8)));
typedef float f32x4 __attribute__((ext_vector_type(4)));
typedef float f32x16 __attribute__((ext_vector_type(16)));

#define NN 131072
#define BM 128
#define WRS 512   // Wb row stride (elems); XOR swizzle handles banks
#define SRS 128   // Sb row stride (staging layout; a0a1 reuses Sb as [64][256])

// WT packed bf16 weights. Two packings:
//  convF  (16x16x32 layers): blocks of 512 = (ctile16 of 16 cols) x (kchunk of 32);
//         within: lane*8+j -> col=ctile*16+(lane&15), k=kch*32+(lane>>4)*8+j.
//  convF32 (32x32x16 layers ND/N1/N2/A0/A1): blocks of 512 = (ctile32 of 32 cols)
//         x (kchunk of 16); within: col=ctile*32+(lane&31), k=kch*16+(lane>>5)*8+j.
// Either way one 1KB wave-load at +lane*16B == one MFMA B fragment.
#define OFF_LD 0
#define OFF_RD 8192
#define OFF_FD 106496
#define OFF_C1 237568
#define OFF_C2 303104
#define OFF_C3 368640
#define OFF_CD 434176
#define OFF_CN 442368
#define OFF_ND 475136
#define OFF_N1 606208
#define OFF_N2 868352
#define OFF_A0 1130496
#define OFF_A1 1654784
#define OFF_N3 2179072
#define WT_TOTAL 2236416

__device__ __forceinline__ unsigned short f2b(float f) {
  __hip_bfloat16 h = __float2bfloat16(f);
  return __builtin_bit_cast(unsigned short, h);
}
__device__ __forceinline__ float b2f(unsigned short u) {
  return __bfloat162float(__builtin_bit_cast(__hip_bfloat16, u));
}

template<int Kd, int Md>
__device__ __forceinline__ unsigned short convF(int local, const float* __restrict__ W) {
  int block = local >> 9;
  int within = local & 511;
  int lane = within >> 3, j = within & 7;
  constexpr int NK = Kd / 32;
  int ctile = block / NK;
  int kch = block - ctile * NK;
  int col = ctile * 16 + (lane & 15);
  int k = kch * 32 + (lane >> 4) * 8 + j;
  return (col < Md) ? f2b(W[(size_t)k * Md + col]) : (unsigned short)0;
}

// 32-col ctile packing for the 32x32x16 layers (dims all multiples of 32).
template<int Kd, int Md>
__device__ __forceinline__ unsigned short convF32(int local, const float* __restrict__ W) {
  int block = local >> 9;
  int within = local & 511;
  int lane = within >> 3, j = within & 7;
  constexpr int NK = Kd / 16;
  int ctile = block / NK;
  int kch = block - ctile * NK;
  int col = ctile * 32 + (lane & 31);
  int k = kch * 16 + (lane >> 5) * 8 + j;
  return f2b(W[(size_t)k * Md + col]);
}

__global__ void prep_weights(const float* __restrict__ Wld, const float* __restrict__ Wrd,
                             const float* __restrict__ Wfd, const float* __restrict__ Wc1,
                             const float* __restrict__ Wc2, const float* __restrict__ Wc3,
                             const float* __restrict__ Wcd, const float* __restrict__ Wcn,
                             const float* __restrict__ Wnd, const float* __restrict__ Wn1,
                             const float* __restrict__ Wn2, const float* __restrict__ Wa0,
                             const float* __restrict__ Wa1, const float* __restrict__ Wn3,
                             unsigned short* __restrict__ WT) {
  int e = blockIdx.x * 256 + threadIdx.x;
  unsigned short r;
  if      (e < OFF_RD) r = convF<64, 128>(e - OFF_LD, Wld);
  else if (e < OFF_FD) r = convF<128, 768>(e - OFF_RD, Wrd);
  else if (e < OFF_C1) r = convF<256, 512>(e - OFF_FD, Wfd);
  else if (e < OFF_C2) r = convF<256, 256>(e - OFF_C1, Wc1);
  else if (e < OFF_C3) r = convF<256, 256>(e - OFF_C2, Wc2);
  else if (e < OFF_CD) r = convF<256, 256>(e - OFF_C3, Wc3);
  else if (e < OFF_CN) r = convF<256, 27>(e - OFF_CD, Wcd);
  else if (e < OFF_ND) r = convF<128, 256>(e - OFF_CN, Wcn);
  else if (e < OFF_N1) r = convF32<256, 512>(e - OFF_ND, Wnd);
  else if (e < OFF_N2) r = convF32<512, 512>(e - OFF_N1, Wn1);
  else if (e < OFF_A0) r = convF32<512, 512>(e - OFF_N2, Wn2);
  else if (e < OFF_A1) r = convF32<512, 1024>(e - OFF_A0, Wa0);
  else if (e < OFF_N3) r = convF32<1024, 512>(e - OFF_A1, Wa1);
  else                 r = convF<512, 101>(e - OFF_N3, Wn3);
  WT[e] = r;
}

// Generic layer, ROW-SPLIT (r13 form): wave = (rh = wid&1 -> rows rh*64..+63,
// cg = wid>>1). acc[4][GSIZE] <= 64 AGPR at GSIZE=4. 16x16x32 MFMA.
// ACT: 0=relu, 1=sigmoid(x), 2=sigmoid(2x).
template<int K, int NOUT, int GSIZE, int ACT, bool TO_GLOBAL, bool ADD>
__device__ __forceinline__ void layer(
    const unsigned short* __restrict__ Ain, int ars,
    const unsigned short* __restrict__ Bw,
    const float* __restrict__ bias,
    unsigned short* __restrict__ Lout, int ors,
    float* __restrict__ Gout, int gld,
    const unsigned short* __restrict__ Aadd, int rsa,
    int lane, int wid) {
  constexpr int NS = K / 32;
  constexpr int NT = (NOUT + 15) >> 4;
  constexpr int NG = (NT + GSIZE - 1) / GSIZE;
  const int cg = wid >> 1;
  const int rbase = (wid & 1) * 64;
  const int l15 = lane & 15;
  const int quad = lane >> 4;
  const int kh = quad << 3;
  const int sw = (l15 & 7) << 3;
  const unsigned short* ab = Ain + (rbase + l15) * ars;
  #pragma unroll 1
  for (int g = cg; g < NG; g += 4) {
    f32x4 acc[4][GSIZE] = {};
    const unsigned short* bp[GSIZE];
    #pragma unroll
    for (int t = 0; t < GSIZE; ++t) {
      int ti = g * GSIZE + t;
      int tc = ti < NT ? ti : NT - 1;   // clamp pad tiles (N3: NT=7, GSIZE=2)
      bp[t] = Bw + (size_t)tc * (NS * 512) + lane * 8;
    }
    __builtin_amdgcn_s_setprio(1);
    #pragma unroll 2
    for (int s = 0; s < NS; ++s) {
      bf16x8 bb[GSIZE];
      #pragma unroll
      for (int t = 0; t < GSIZE; ++t) bb[t] = *(const bf16x8*)(bp[t] + s * 512);
      int kx = (kh + s * 32) ^ sw;
      #pragma unroll
      for (int m = 0; m < 4; ++m) {
        bf16x8 a = *(const bf16x8*)(ab + m * 16 * ars + kx);
        #pragma unroll
        for (int t = 0; t < GSIZE; ++t)
          acc[m][t] = __builtin_amdgcn_mfma_f32_16x16x32_bf16(a, bb[t], acc[m][t], 0, 0, 0);
      }
    }
    __builtin_amdgcn_s_setprio(0);
    #pragma unroll
    for (int t = 0; t < GSIZE; ++t) {
      int col = (g * GSIZE + t) * 16 + l15;
      int cc = col < NOUT ? col : NOUT - 1;
      float bb2 = bias[cc];
      #pragma unroll
      for (int m = 0; m < 4; ++m) {
        #pragma unroll
        for (int j = 0; j < 4; ++j) {
          int row = rbase + m * 16 + quad * 4 + j;
          int rsw = (row & 7) << 3;
          float v = acc[m][t][j] + bb2;
          if constexpr (ACT == 0) v = fmaxf(v, 0.f);
          else if constexpr (ACT == 1) v = 1.f / (1.f + __expf(-v));
          else if constexpr (ACT == 2) v = 1.f / (1.f + __expf(-2.f * v));
          if constexpr (ADD) v += b2f(Aadd[row * rsa + (col ^ rsw)]);
          if constexpr (TO_GLOBAL) {
            if (col < NOUT) Gout[(size_t)row * gld + col] = v;
          } else {
            Lout[row * ors + (col ^ rsw)] = f2b(v);
          }
        }
      }
    }
  }
}

// 512-wide relu layer, in-place on Wb, 32x32x16 MFMA. Wave = (rh rows 64, cg
// cols 128 = 4 ctile32). acc[2][4] f32x16 = 128 AGPR. Per k=16 step: 2 A-reads
// + 4 B-loads + 8 MFMA (half the instructions of the 16x16 version).
// C/D layout: col=lane&31, row=(reg&3)+8*(reg>>2)+4*(lane>>5)  [m74/m101].
template<int K>
__device__ __forceinline__ void layer512_ip(
    unsigned short* __restrict__ Wb,
    const unsigned short* __restrict__ Bw, const float* __restrict__ bias,
    int lane, int wid) {
  constexpr int NS = K / 16;
  const int cg = wid >> 1;             // cols cg*128..+127 (ctile32 cg*4..+3)
  const int rbase = (wid & 1) * 64;
  const int l31 = lane & 31;
  const int kh32 = (lane >> 5) << 3;
  const int sw32 = (lane & 7) << 3;
  f32x16 acc[2][4] = {};
  const unsigned short* bp = Bw + (size_t)(cg * 4) * (NS * 512) + lane * 8;
  const unsigned short* ab = Wb + (rbase + l31) * WRS;
  __builtin_amdgcn_s_setprio(1);
  #pragma unroll 2
  for (int s = 0; s < NS; ++s) {
    bf16x8 bb[4];
    #pragma unroll
    for (int t = 0; t < 4; ++t) bb[t] = *(const bf16x8*)(bp + (size_t)t * (NS * 512) + s * 512);
    int kx = (kh32 + s * 16) ^ sw32;
    #pragma unroll
    for (int rt = 0; rt < 2; ++rt) {
      bf16x8 a = *(const bf16x8*)(ab + rt * 32 * WRS + kx);
      #pragma unroll
      for (int t = 0; t < 4; ++t)
        acc[rt][t] = __builtin_amdgcn_mfma_f32_32x32x16_bf16(a, bb[t], acc[rt][t], 0, 0, 0);
    }
  }
  __builtin_amdgcn_s_setprio(0);
  __syncthreads();   // all reads of Wb done -> safe to overwrite
  #pragma unroll
  for (int t = 0; t < 4; ++t) {
    int col = cg * 128 + t * 32 + l31;
    float bb2 = bias[col];
    #pragma unroll
    for (int rt = 0; rt < 2; ++rt) {
      #pragma unroll
      for (int r = 0; r < 16; ++r) {
        int row = rbase + rt * 32 + (r & 3) + 8 * (r >> 2) + 4 * (lane >> 5);
        Wb[row * WRS + (col ^ ((row & 7) << 3))] = f2b(fmaxf(acc[rt][t][r] + bb2, 0.f));
      }
    }
  }
  __syncthreads();
}

__global__ __launch_bounds__(512, 2)
void fused_vae(const float* __restrict__ z, const int* __restrict__ cind,
               const float* __restrict__ Emb,
               const float* __restrict__ bld, const float* __restrict__ brd,
               const float* __restrict__ bfd, const float* __restrict__ bc1,
               const float* __restrict__ bc2, const float* __restrict__ bc3,
               const float* __restrict__ bcd, const float* __restrict__ bcn,
               const float* __restrict__ bnd, const float* __restrict__ bn1,
               const float* __restrict__ bn2, const float* __restrict__ ba0,
               const float* __restrict__ ba1, const float* __restrict__ bn3,
               const unsigned short* __restrict__ WT, float* __restrict__ out) {
  // 128*512 + 128*128 bf16 = 163840 B = full 160 KiB LDS, 1 block/CU
  __shared__ unsigned short lds[BM * (WRS + SRS)];
  unsigned short* Wb = lds;            // [128][512] swizzled
  unsigned short* Sb = lds + BM * WRS; // [128][128] staging; [64][256] in a0a1
  const int tid = threadIdx.x;
  const int lane = tid & 63;
  const int wid = tid >> 6;
  const size_t row0 = (size_t)blockIdx.x * BM;

  // stage z -> Wb[:, 0:64]
  for (int e = tid * 4; e < BM * 64; e += 512 * 4) {
    int r = e >> 6, c = e & 63;
    float4 v = *(const float4*)(z + (row0 + r) * 64 + c);
    ushort4 u; u.x = f2b(v.x); u.y = f2b(v.y); u.z = f2b(v.z); u.w = f2b(v.w);
    *(ushort4*)(&Wb[r * WRS + (c ^ ((r & 7) << 3))]) = u;
  }
  __syncthreads();
  // z1 = relu(z @ Wld + bld) -> Sb [128][128]
  layer<64, 128, 2, 0, false, false>(Wb, WRS, WT + OFF_LD, bld, Sb, SRS, nullptr, 0, nullptr, 0, lane, wid);
  __syncthreads();
  // cl_h -> Wb[0:256]   (RD ctiles 32..47 = cols 512..767)
  layer<128, 256, 4, 0, false, false>(Sb, SRS, WT + OFF_RD + (size_t)32 * 4 * 512, brd + 512, Wb, WRS, nullptr, 0, nullptr, 0, lane, wid);
  __syncthreads();
  layer<256, 256, 4, 0, false, false>(Wb, WRS, WT + OFF_C1, bc1, Wb + 256, WRS, nullptr, 0, nullptr, 0, lane, wid);
  __syncthreads();
  layer<256, 256, 4, 0, false, false>(Wb + 256, WRS, WT + OFF_C2, bc2, Wb, WRS, nullptr, 0, nullptr, 0, lane, wid);
  __syncthreads();
  layer<256, 256, 4, 0, false, false>(Wb, WRS, WT + OFF_C3, bc3, Wb + 256, WRS, nullptr, 0, nullptr, 0, lane, wid);
  __syncthreads();
  // cluster -> global (reads Wb[256:512])  ||  feat_h -> Wb[0:256]
  layer<256, 27, 1, 2, true, false>(Wb + 256, WRS, WT + OFF_CD, bcd, nullptr, 0,
                                    out + (size_t)NN * 613 + row0 * 27, 27, nullptr, 0, lane, wid);
  layer<128, 256, 4, 0, false, false>(Sb, SRS, WT + OFF_RD, brd, Wb, WRS, nullptr, 0, nullptr, 0, lane, wid);
  __syncthreads();
  // feat -> global (reads Wb[0:256])  ||  nb_h -> Wb[256:512]  (RD ctiles 16..31)
  layer<256, 512, 4, 1, true, false>(Wb, WRS, WT + OFF_FD, bfd, nullptr, 0,
                                     out + row0 * 512, 512, nullptr, 0, lane, wid);
  layer<128, 256, 4, 0, false, false>(Sb, SRS, WT + OFF_RD + (size_t)16 * 4 * 512, brd + 256, Wb + 256, WRS, nullptr, 0, nullptr, 0, lane, wid);
  __syncthreads();
  // stage emb -> Sb (z1 dead)
  for (int e = tid * 4; e < BM * 128; e += 512 * 4) {
    int r = e >> 7, c = e & 127;
    int ci = cind[row0 + r];
    float4 v = *(const float4*)(Emb + (size_t)ci * 128 + c);
    ushort4 u; u.x = f2b(v.x); u.y = f2b(v.y); u.z = f2b(v.z); u.w = f2b(v.w);
    *(ushort4*)(&Sb[r * SRS + (c ^ ((r & 7) << 3))]) = u;
  }
  __syncthreads();
  // x = relu(emb @ Wcn + bcn) + nb_h -> Wb[0:256] (ADD reads Wb[256:512])
  layer<128, 256, 4, 0, false, true>(Sb, SRS, WT + OFF_CN, bcn, Wb, WRS, nullptr, 0, Wb + 256, WRS, lane, wid);
  __syncthreads();
  // nf1 (K=256 reads Wb[0:256]), nf2, nf3: in-place, 32x32 MFMA
  layer512_ip<256>(Wb, WT + OFF_ND, bnd, lane, wid);
  layer512_ip<512>(Wb, WT + OFF_N1, bn1, lane, wid);
  layer512_ip<512>(Wb, WT + OFF_N2, bn2, lane, wid);
  // a0/a1 fused (32x32 MFMA), rh loop over two 64-row passes; a0 in FOUR
  // 256-col chunks through single-buffered Sb[64][256].
  //   a0: wave = 32 rows (irh=wid&1) x 64 cols (cga=wid>>1, 2 ctile32):
  //       acc0[2] f32x16 = 32 AGPR; per k=16 step: 1 A + 2 B + 2 MFMA.
  //   a1: wave = 64 rows x 64 cols (wid -> 2 ctile32): acc1[2][2] f32x16 = 64.
  {
    const int l31 = lane & 31;
    const int kh32 = (lane >> 5) << 3;
    const int sw32 = (lane & 7) << 3;
    const int irh = wid & 1;
    const int cga = wid >> 1;          // 0..3
    #pragma unroll 1
    for (int rh = 0; rh < 2; ++rh) {
      f32x16 acc1[2][2] = {};
      const unsigned short* awb0 = Wb + (rh * 64 + irh * 32 + l31) * WRS;
      const unsigned short* asb = Sb + l31 * 256;
      #pragma unroll 1
      for (int e = 0; e < 4; ++e) {
        // a0 chunk: cols e*256..+255; wave owns ctile32 (e*8 + cga*2) + {0,1}
        f32x16 acc0[2] = {};
        const unsigned short* bp0 = WT + OFF_A0 + (size_t)(e * 8 + cga * 2) * (32 * 512) + lane * 8;
        __builtin_amdgcn_s_setprio(1);
        #pragma unroll 2
        for (int s = 0; s < 32; ++s) {
          bf16x8 b0 = *(const bf16x8*)(bp0 + s * 512);
          bf16x8 b1 = *(const bf16x8*)(bp0 + 32 * 512 + s * 512);
          int kx = (kh32 + s * 16) ^ sw32;
          bf16x8 a = *(const bf16x8*)(awb0 + kx);
          acc0[0] = __builtin_amdgcn_mfma_f32_32x32x16_bf16(a, b0, acc0[0], 0, 0, 0);
          acc0[1] = __builtin_amdgcn_mfma_f32_32x32x16_bf16(a, b1, acc0[1], 0, 0, 0);
        }
        __builtin_amdgcn_s_setprio(0);
        __syncthreads();   // prev chunk's a1 reads of Sb done
        #pragma unroll
        for (int ct = 0; ct < 2; ++ct) {
          int lc = cga * 64 + ct * 32 + l31;
          float bb2 = ba0[e * 256 + lc];
          #pragma unroll
          for (int r = 0; r < 16; ++r) {
            int row = irh * 32 + (r & 3) + 8 * (r >> 2) + 4 * (lane >> 5);  // local 0..63
            Sb[row * 256 + (lc ^ ((row & 7) << 3))] = f2b(fmaxf(acc0[ct][r] + bb2, 0.f));
          }
        }
        __syncthreads();
        // a1 partial: k = e*256..+255 (kchunk16 e*16..+15) from Sb[64][256]
        const unsigned short* bp1 = WT + OFF_A1 + (size_t)(wid * 2) * (64 * 512) + (size_t)(e * 16) * 512 + lane * 8;
        __builtin_amdgcn_s_setprio(1);
        #pragma unroll 2
        for (int s = 0; s < 16; ++s) {
          bf16x8 b0 = *(const bf16x8*)(bp1 + s * 512);
          bf16x8 b1 = *(const bf16x8*)(bp1 + 64 * 512 + s * 512);
          int kx = (kh32 + s * 16) ^ sw32;
          #pragma unroll
          for (int rt = 0; rt < 2; ++rt) {
            bf16x8 a = *(const bf16x8*)(asb + rt * 32 * 256 + kx);
            acc1[rt][0] = __builtin_amdgcn_mfma_f32_32x32x16_bf16(a, b0, acc1[rt][0], 0, 0, 0);
            acc1[rt][1] = __builtin_amdgcn_mfma_f32_32x32x16_bf16(a, b1, acc1[rt][1], 0, 0, 0);
          }
        }
        __builtin_amdgcn_s_setprio(0);
      }
      // a1 rows rh*64..+63 -> Wb in place (all a0 reads of these rows finished
      // before chunk 3's barriers; a1 reads only Sb)
      #pragma unroll
      for (int rt = 0; rt < 2; ++rt) {
        #pragma unroll
        for (int ct = 0; ct < 2; ++ct) {
          int col = wid * 64 + ct * 32 + l31;
          float bb2 = ba1[col];
          #pragma unroll
          for (int r = 0; r < 16; ++r) {
            int row = rh * 64 + rt * 32 + (r & 3) + 8 * (r >> 2) + 4 * (lane >> 5);
            Wb[row * WRS + (col ^ ((row & 7) << 3))] = f2b(fmaxf(acc1[rt][ct][r] + bb2, 0.f));
          }
        }
      }
    }
  }
  __syncthreads();
  // neighbor_map = sigmoid(2*(a1 @ Wn3 + bn3)) -> global
  layer<512, 101, 2, 2, true, false>(Wb, WRS, WT + OFF_N3, bn3, nullptr, 0,
                                     out + (size_t)NN * 512 + row0 * 101, 101, nullptr, 0, lane, wid);
}

extern "C" void kernel_launch(void* const* d_in, const int* in_sizes, int n_in,
                              void* d_out, int out_size, void* d_ws, size_t ws_size,
                              hipStream_t stream) {
  const float* z   = (const float*)d_in[0];
  const int*   cind= (const int*)d_in[1];
  const float* Emb = (const float*)d_in[2];
  const float* Wld = (const float*)d_in[3];  const float* bld = (const float*)d_in[4];
  const float* Wrd = (const float*)d_in[5];  const float* brd = (const float*)d_in[6];
  const float* Wfd = (const float*)d_in[7];  const float* bfd = (const float*)d_in[8];
  const float* Wc1 = (const float*)d_in[9];  const float* bc1 = (const float*)d_in[10];
  const float* Wc2 = (const float*)d_in[11]; const float* bc2 = (const float*)d_in[12];
  const float* Wc3 = (const float*)d_in[13]; const float* bc3 = (const float*)d_in[14];
  const float* Wcd = (const float*)d_in[15]; const float* bcd = (const float*)d_in[16];
  const float* Wcn = (const float*)d_in[17]; const float* bcn = (const float*)d_in[18];
  const float* Wnd = (const float*)d_in[19]; const float* bnd = (const float*)d_in[20];
  const float* Wn1 = (const float*)d_in[21]; const float* bn1 = (const float*)d_in[22];
  const float* Wn2 = (const float*)d_in[23]; const float* bn2 = (const float*)d_in[24];
  const float* Wa0 = (const float*)d_in[25]; const float* ba0 = (const float*)d_in[26];
  const float* Wa1 = (const float*)d_in[27]; const float* ba1 = (const float*)d_in[28];
  const float* Wn3 = (const float*)d_in[29]; const float* bn3 = (const float*)d_in[30];
  unsigned short* WT = (unsigned short*)d_ws;
  float* out = (float*)d_out;

  prep_weights<<<WT_TOTAL / 256, 256, 0, stream>>>(Wld, Wrd, Wfd, Wc1, Wc2, Wc3, Wcd,
                                                   Wcn, Wnd, Wn1, Wn2, Wa0, Wa1, Wn3, WT);
  fused_vae<<<NN / BM, 512, 0, stream>>>(z, cind, Emb, bld, brd, bfd, bc1, bc2, bc3,
                                         bcd, bcn, bnd, bn1, bn2, ba0, ba1, bn3, WT, out);
}

// Round 17
// 660.853 us; speedup vs baseline: 1.1955x; 1.1955x over previous
//
#include <hip/hip_runtime.h>
#include <hip/hip_bf16.h>

typedef short bf16x8 __attribute__((ext_vector_type(8)));
typedef float f32x4 __attribute__((ext_vector_type(4)));

#define NN 131072
#define BM 128
#define WRS 512   // Wb row stride (elems); XOR swizzle handles banks
#define SRS 128   // Sb row stride (staging layout; a0a1 reuses Sb as [64][256])

// WT fragment-packed bf16 weights (see convF): per layer, blocks of 512 elems
// indexed (ctile*(K/32) + kchunk); within-block lane*8+j = (k=kch*32+(lane>>4)*8+j,
// col=ctile*16+(lane&15)). One 1KB wave-load at +lane*16B == one MFMA B fragment.
#define OFF_LD 0
#define OFF_RD 8192
#define OFF_FD 106496
#define OFF_C1 237568
#define OFF_C2 303104
#define OFF_C3 368640
#define OFF_CD 434176
#define OFF_CN 442368
#define OFF_ND 475136
#define OFF_N1 606208
#define OFF_N2 868352
#define OFF_A0 1130496
#define OFF_A1 1654784
#define OFF_N3 2179072
#define WT_TOTAL 2236416

__device__ __forceinline__ unsigned short f2b(float f) {
  __hip_bfloat16 h = __float2bfloat16(f);
  return __builtin_bit_cast(unsigned short, h);
}
__device__ __forceinline__ float b2f(unsigned short u) {
  return __bfloat162float(__builtin_bit_cast(__hip_bfloat16, u));
}

template<int Kd, int Md>
__device__ __forceinline__ unsigned short convF(int local, const float* __restrict__ W) {
  int block = local >> 9;
  int within = local & 511;
  int lane = within >> 3, j = within & 7;
  constexpr int NK = Kd / 32;
  int ctile = block / NK;
  int kch = block - ctile * NK;
  int col = ctile * 16 + (lane & 15);
  int k = kch * 32 + (lane >> 4) * 8 + j;
  return (col < Md) ? f2b(W[(size_t)k * Md + col]) : (unsigned short)0;
}

__global__ void prep_weights(const float* __restrict__ Wld, const float* __restrict__ Wrd,
                             const float* __restrict__ Wfd, const float* __restrict__ Wc1,
                             const float* __restrict__ Wc2, const float* __restrict__ Wc3,
                             const float* __restrict__ Wcd, const float* __restrict__ Wcn,
                             const float* __restrict__ Wnd, const float* __restrict__ Wn1,
                             const float* __restrict__ Wn2, const float* __restrict__ Wa0,
                             const float* __restrict__ Wa1, const float* __restrict__ Wn3,
                             unsigned short* __restrict__ WT) {
  int e = blockIdx.x * 256 + threadIdx.x;
  unsigned short r;
  if      (e < OFF_RD) r = convF<64, 128>(e - OFF_LD, Wld);
  else if (e < OFF_FD) r = convF<128, 768>(e - OFF_RD, Wrd);
  else if (e < OFF_C1) r = convF<256, 512>(e - OFF_FD, Wfd);
  else if (e < OFF_C2) r = convF<256, 256>(e - OFF_C1, Wc1);
  else if (e < OFF_C3) r = convF<256, 256>(e - OFF_C2, Wc2);
  else if (e < OFF_CD) r = convF<256, 256>(e - OFF_C3, Wc3);
  else if (e < OFF_CN) r = convF<256, 27>(e - OFF_CD, Wcd);
  else if (e < OFF_ND) r = convF<128, 256>(e - OFF_CN, Wcn);
  else if (e < OFF_N1) r = convF<256, 512>(e - OFF_ND, Wnd);
  else if (e < OFF_N2) r = convF<512, 512>(e - OFF_N1, Wn1);
  else if (e < OFF_A0) r = convF<512, 512>(e - OFF_N2, Wn2);
  else if (e < OFF_A1) r = convF<512, 1024>(e - OFF_A0, Wa0);
  else if (e < OFF_N3) r = convF<1024, 512>(e - OFF_A1, Wa1);
  else                 r = convF<512, 101>(e - OFF_N3, Wn3);
  WT[e] = r;
}

// Generic layer, ROW-SPLIT: wave = (rh = wid&1 -> rows rh*64..+63, cg = wid>>1).
// acc[4][GSIZE] <= 64 AGPR at GSIZE=4. 16x16x32 MFMA.
// ACT: 0=relu, 1=sigmoid(x), 2=sigmoid(2x).
template<int K, int NOUT, int GSIZE, int ACT, bool TO_GLOBAL, bool ADD>
__device__ __forceinline__ void layer(
    const unsigned short* __restrict__ Ain, int ars,
    const unsigned short* __restrict__ Bw,
    const float* __restrict__ bias,
    unsigned short* __restrict__ Lout, int ors,
    float* __restrict__ Gout, int gld,
    const unsigned short* __restrict__ Aadd, int rsa,
    int lane, int wid) {
  constexpr int NS = K / 32;
  constexpr int NT = (NOUT + 15) >> 4;
  constexpr int NG = (NT + GSIZE - 1) / GSIZE;
  const int cg = wid >> 1;
  const int rbase = (wid & 1) * 64;
  const int l15 = lane & 15;
  const int quad = lane >> 4;
  const int kh = quad << 3;
  const int sw = (l15 & 7) << 3;
  const unsigned short* ab = Ain + (rbase + l15) * ars;
  #pragma unroll 1
  for (int g = cg; g < NG; g += 4) {
    f32x4 acc[4][GSIZE] = {};
    const unsigned short* bp[GSIZE];
    #pragma unroll
    for (int t = 0; t < GSIZE; ++t) {
      int ti = g * GSIZE + t;
      int tc = ti < NT ? ti : NT - 1;   // clamp pad tiles (N3: NT=7, GSIZE=2)
      bp[t] = Bw + (size_t)tc * (NS * 512) + lane * 8;
    }
    __builtin_amdgcn_s_setprio(1);
    #pragma unroll 2
    for (int s = 0; s < NS; ++s) {
      bf16x8 bb[GSIZE];
      #pragma unroll
      for (int t = 0; t < GSIZE; ++t) bb[t] = *(const bf16x8*)(bp[t] + s * 512);
      int kx = (kh + s * 32) ^ sw;
      #pragma unroll
      for (int m = 0; m < 4; ++m) {
        bf16x8 a = *(const bf16x8*)(ab + m * 16 * ars + kx);
        #pragma unroll
        for (int t = 0; t < GSIZE; ++t)
          acc[m][t] = __builtin_amdgcn_mfma_f32_16x16x32_bf16(a, bb[t], acc[m][t], 0, 0, 0);
      }
    }
    __builtin_amdgcn_s_setprio(0);
    #pragma unroll
    for (int t = 0; t < GSIZE; ++t) {
      int col = (g * GSIZE + t) * 16 + l15;
      int cc = col < NOUT ? col : NOUT - 1;
      float bb2 = bias[cc];
      #pragma unroll
      for (int m = 0; m < 4; ++m) {
        #pragma unroll
        for (int j = 0; j < 4; ++j) {
          int row = rbase + m * 16 + quad * 4 + j;
          int rsw = (row & 7) << 3;
          float v = acc[m][t][j] + bb2;
          if constexpr (ACT == 0) v = fmaxf(v, 0.f);
          else if constexpr (ACT == 1) v = 1.f / (1.f + __expf(-v));
          else if constexpr (ACT == 2) v = 1.f / (1.f + __expf(-2.f * v));
          if constexpr (ADD) v += b2f(Aadd[row * rsa + (col ^ rsw)]);
          if constexpr (TO_GLOBAL) {
            if (col < NOUT) Gout[(size_t)row * gld + col] = v;
          } else {
            Lout[row * ors + (col ^ rsw)] = f2b(v);
          }
        }
      }
    }
  }
}

// 512-wide relu layer, in-place on Wb, ROW-SPLIT 2 x cg 4 (1:8 A:MFMA).
// acc[4][8]=128 AGPR; unroll 2 bounds the live load-register window.
template<int K>
__device__ __forceinline__ void layer512_ip(
    unsigned short* __restrict__ Wb,
    const unsigned short* __restrict__ Bw, const float* __restrict__ bias,
    int lane, int wid) {
  constexpr int NS = K / 32;
  const int cg = wid >> 1;             // cols cg*128..+127 (ctiles cg*8..+7)
  const int rbase = (wid & 1) * 64;
  const int l15 = lane & 15;
  const int quad = lane >> 4;
  const int kh = quad << 3;
  const int sw = (l15 & 7) << 3;
  f32x4 acc[4][8] = {};
  const unsigned short* bp = Bw + (size_t)(cg * 8) * (NS * 512) + lane * 8;
  const unsigned short* ab = Wb + (rbase + l15) * WRS;
  __builtin_amdgcn_s_setprio(1);
  #pragma unroll 2
  for (int s = 0; s < NS; ++s) {
    bf16x8 bb[8];
    #pragma unroll
    for (int t = 0; t < 8; ++t) bb[t] = *(const bf16x8*)(bp + (size_t)t * (NS * 512) + s * 512);
    int kx = (kh + s * 32) ^ sw;
    #pragma unroll
    for (int m = 0; m < 4; ++m) {
      bf16x8 a = *(const bf16x8*)(ab + m * 16 * WRS + kx);
      #pragma unroll
      for (int t = 0; t < 8; ++t)
        acc[m][t] = __builtin_amdgcn_mfma_f32_16x16x32_bf16(a, bb[t], acc[m][t], 0, 0, 0);
    }
  }
  __builtin_amdgcn_s_setprio(0);
  __syncthreads();   // all reads of Wb done -> safe to overwrite
  #pragma unroll
  for (int t = 0; t < 8; ++t) {
    int col = cg * 128 + t * 16 + l15;
    float bb2 = bias[col];
    #pragma unroll
    for (int m = 0; m < 4; ++m) {
      #pragma unroll
      for (int j = 0; j < 4; ++j) {
        int row = rbase + m * 16 + quad * 4 + j;
        Wb[row * WRS + (col ^ ((row & 7) << 3))] = f2b(fmaxf(acc[m][t][j] + bb2, 0.f));
      }
    }
  }
  __syncthreads();
}

__global__ __launch_bounds__(512, 2)
void fused_vae(const float* __restrict__ z, const int* __restrict__ cind,
               const float* __restrict__ Emb,
               const float* __restrict__ bld, const float* __restrict__ brd,
               const float* __restrict__ bfd, const float* __restrict__ bc1,
               const float* __restrict__ bc2, const float* __restrict__ bc3,
               const float* __restrict__ bcd, const float* __restrict__ bcn,
               const float* __restrict__ bnd, const float* __restrict__ bn1,
               const float* __restrict__ bn2, const float* __restrict__ ba0,
               const float* __restrict__ ba1, const float* __restrict__ bn3,
               const unsigned short* __restrict__ WT, float* __restrict__ out) {
  // 128*512 + 128*128 bf16 = 163840 B = full 160 KiB LDS, 1 block/CU
  __shared__ unsigned short lds[BM * (WRS + SRS)];
  unsigned short* Wb = lds;            // [128][512] swizzled
  unsigned short* Sb = lds + BM * WRS; // [128][128] staging; [64][256] in a0a1
  const int tid = threadIdx.x;
  const int lane = tid & 63;
  const int wid = tid >> 6;
  const size_t row0 = (size_t)blockIdx.x * BM;

  // stage z -> Wb[:, 0:64]
  for (int e = tid * 4; e < BM * 64; e += 512 * 4) {
    int r = e >> 6, c = e & 63;
    float4 v = *(const float4*)(z + (row0 + r) * 64 + c);
    ushort4 u; u.x = f2b(v.x); u.y = f2b(v.y); u.z = f2b(v.z); u.w = f2b(v.w);
    *(ushort4*)(&Wb[r * WRS + (c ^ ((r & 7) << 3))]) = u;
  }
  __syncthreads();
  // z1 = relu(z @ Wld + bld) -> Sb [128][128]
  layer<64, 128, 2, 0, false, false>(Wb, WRS, WT + OFF_LD, bld, Sb, SRS, nullptr, 0, nullptr, 0, lane, wid);
  __syncthreads();
  // cl_h -> Wb[0:256]   (RD ctiles 32..47 = cols 512..767)
  layer<128, 256, 4, 0, false, false>(Sb, SRS, WT + OFF_RD + (size_t)32 * 4 * 512, brd + 512, Wb, WRS, nullptr, 0, nullptr, 0, lane, wid);
  __syncthreads();
  layer<256, 256, 4, 0, false, false>(Wb, WRS, WT + OFF_C1, bc1, Wb + 256, WRS, nullptr, 0, nullptr, 0, lane, wid);
  __syncthreads();
  layer<256, 256, 4, 0, false, false>(Wb + 256, WRS, WT + OFF_C2, bc2, Wb, WRS, nullptr, 0, nullptr, 0, lane, wid);
  __syncthreads();
  layer<256, 256, 4, 0, false, false>(Wb, WRS, WT + OFF_C3, bc3, Wb + 256, WRS, nullptr, 0, nullptr, 0, lane, wid);
  __syncthreads();
  // cluster -> global (reads Wb[256:512])  ||  feat_h -> Wb[0:256]
  layer<256, 27, 1, 2, true, false>(Wb + 256, WRS, WT + OFF_CD, bcd, nullptr, 0,
                                    out + (size_t)NN * 613 + row0 * 27, 27, nullptr, 0, lane, wid);
  layer<128, 256, 4, 0, false, false>(Sb, SRS, WT + OFF_RD, brd, Wb, WRS, nullptr, 0, nullptr, 0, lane, wid);
  __syncthreads();
  // feat -> global (reads Wb[0:256])  ||  nb_h -> Wb[256:512]  (RD ctiles 16..31)
  layer<256, 512, 4, 1, true, false>(Wb, WRS, WT + OFF_FD, bfd, nullptr, 0,
                                     out + row0 * 512, 512, nullptr, 0, lane, wid);
  layer<128, 256, 4, 0, false, false>(Sb, SRS, WT + OFF_RD + (size_t)16 * 4 * 512, brd + 256, Wb + 256, WRS, nullptr, 0, nullptr, 0, lane, wid);
  __syncthreads();
  // stage emb -> Sb (z1 dead)
  for (int e = tid * 4; e < BM * 128; e += 512 * 4) {
    int r = e >> 7, c = e & 127;
    int ci = cind[row0 + r];
    float4 v = *(const float4*)(Emb + (size_t)ci * 128 + c);
    ushort4 u; u.x = f2b(v.x); u.y = f2b(v.y); u.z = f2b(v.z); u.w = f2b(v.w);
    *(ushort4*)(&Sb[r * SRS + (c ^ ((r & 7) << 3))]) = u;
  }
  __syncthreads();
  // x = relu(emb @ Wcn + bcn) + nb_h -> Wb[0:256] (ADD reads Wb[256:512])
  layer<128, 256, 4, 0, false, true>(Sb, SRS, WT + OFF_CN, bcn, Wb, WRS, nullptr, 0, Wb + 256, WRS, lane, wid);
  __syncthreads();
  // nf1 (K=256 reads Wb[0:256]), nf2, nf3: in-place, row-split
  layer512_ip<256>(Wb, WT + OFF_ND, bnd, lane, wid);
  layer512_ip<512>(Wb, WT + OFF_N1, bn1, lane, wid);
  layer512_ip<512>(Wb, WT + OFF_N2, bn2, lane, wid);
  // a0/a1 fused, rh loop over two 64-row passes; a0 in FOUR 256-col chunks
  // through single-buffered Sb[64][256]. Wave split: a0 = 64 rows x 32 cols
  // (2 ctiles, acc0[4][2]=32); a1 = 64 rows x 64 cols (4 ctiles, acc1[4][4]=64).
  {
    const int l15 = lane & 15;
    const int quad = lane >> 4;
    const int kh = quad << 3;
    const int sw = (l15 & 7) << 3;
    #pragma unroll 1
    for (int rh = 0; rh < 2; ++rh) {
      f32x4 acc1[4][4] = {};
      const unsigned short* awb = Wb + (rh * 64 + l15) * WRS;
      const unsigned short* asb = Sb + l15 * 256;
      #pragma unroll 1
      for (int e = 0; e < 4; ++e) {
        // a0 chunk: cols e*256..+255; wave owns ctiles e*16 + wid*2 + {0,1}
        f32x4 acc0[4][2] = {};
        const unsigned short* bp0 = WT + OFF_A0 + (size_t)(e * 16 + wid * 2) * (16 * 512) + lane * 8;
        __builtin_amdgcn_s_setprio(1);
        #pragma unroll 2
        for (int s = 0; s < 16; ++s) {
          bf16x8 b0 = *(const bf16x8*)(bp0 + s * 512);
          bf16x8 b1 = *(const bf16x8*)(bp0 + 16 * 512 + s * 512);
          int kx = (kh + s * 32) ^ sw;
          #pragma unroll
          for (int m = 0; m < 4; ++m) {
            bf16x8 a = *(const bf16x8*)(awb + m * 16 * WRS + kx);
            acc0[m][0] = __builtin_amdgcn_mfma_f32_16x16x32_bf16(a, b0, acc0[m][0], 0, 0, 0);
            acc0[m][1] = __builtin_amdgcn_mfma_f32_16x16x32_bf16(a, b1, acc0[m][1], 0, 0, 0);
          }
        }
        __builtin_amdgcn_s_setprio(0);
        __syncthreads();   // prev chunk's a1 reads of Sb done
        #pragma unroll
        for (int t = 0; t < 2; ++t) {
          int lc = wid * 32 + t * 16 + l15;
          float bb2 = ba0[e * 256 + lc];
          #pragma unroll
          for (int m = 0; m < 4; ++m) {
            #pragma unroll
            for (int j = 0; j < 4; ++j) {
              int row = m * 16 + quad * 4 + j;   // local 0..63
              Sb[row * 256 + (lc ^ ((row & 7) << 3))] = f2b(fmaxf(acc0[m][t][j] + bb2, 0.f));
            }
          }
        }
        __syncthreads();
        // a1 partial: kchunks e*8..e*8+7 from Sb[64][256]
        const unsigned short* bp1 = WT + OFF_A1 + (size_t)(wid * 4) * (32 * 512) + (size_t)(e * 8) * 512 + lane * 8;
        __builtin_amdgcn_s_setprio(1);
        #pragma unroll 2
        for (int s = 0; s < 8; ++s) {
          bf16x8 b[4];
          #pragma unroll
          for (int t = 0; t < 4; ++t) b[t] = *(const bf16x8*)(bp1 + (size_t)t * (32 * 512) + s * 512);
          int kx = (kh + s * 32) ^ sw;
          #pragma unroll
          for (int m = 0; m < 4; ++m) {
            bf16x8 a = *(const bf16x8*)(asb + m * 16 * 256 + kx);
            #pragma unroll
            for (int t = 0; t < 4; ++t)
              acc1[m][t] = __builtin_amdgcn_mfma_f32_16x16x32_bf16(a, b[t], acc1[m][t], 0, 0, 0);
          }
        }
        __builtin_amdgcn_s_setprio(0);
      }
      // a1 rows rh*64..+63 -> Wb in place (all a0 reads of these rows finished
      // before chunk 3's barriers; a1 reads only Sb)
      #pragma unroll
      for (int t = 0; t < 4; ++t) {
        int col = wid * 64 + t * 16 + l15;
        float bb2 = ba1[col];
        #pragma unroll
        for (int m = 0; m < 4; ++m) {
          #pragma unroll
          for (int j = 0; j < 4; ++j) {
            int row = rh * 64 + m * 16 + quad * 4 + j;
            Wb[row * WRS + (col ^ ((row & 7) << 3))] = f2b(fmaxf(acc1[m][t][j] + bb2, 0.f));
          }
        }
      }
    }
  }
  __syncthreads();
  // neighbor_map = sigmoid(2*(a1 @ Wn3 + bn3)) -> global
  layer<512, 101, 2, 2, true, false>(Wb, WRS, WT + OFF_N3, bn3, nullptr, 0,
                                     out + (size_t)NN * 512 + row0 * 101, 101, nullptr, 0, lane, wid);
}

extern "C" void kernel_launch(void* const* d_in, const int* in_sizes, int n_in,
                              void* d_out, int out_size, void* d_ws, size_t ws_size,
                              hipStream_t stream) {
  const float* z   = (const float*)d_in[0];
  const int*   cind= (const int*)d_in[1];
  const float* Emb = (const float*)d_in[2];
  const float* Wld = (const float*)d_in[3];  const float* bld = (const float*)d_in[4];
  const float* Wrd = (const float*)d_in[5];  const float* brd = (const float*)d_in[6];
  const float* Wfd = (const float*)d_in[7];  const float* bfd = (const float*)d_in[8];
  const float* Wc1 = (const float*)d_in[9];  const float* bc1 = (const float*)d_in[10];
  const float* Wc2 = (const float*)d_in[11]; const float* bc2 = (const float*)d_in[12];
  const float* Wc3 = (const float*)d_in[13]; const float* bc3 = (const float*)d_in[14];
  const float* Wcd = (const float*)d_in[15]; const float* bcd = (const float*)d_in[16];
  const float* Wcn = (const float*)d_in[17]; const float* bcn = (const float*)d_in[18];
  const float* Wnd = (const float*)d_in[19]; const float* bnd = (const float*)d_in[20];
  const float* Wn1 = (const float*)d_in[21]; const float* bn1 = (const float*)d_in[22];
  const float* Wn2 = (const float*)d_in[23]; const float* bn2 = (const float*)d_in[24];
  const float* Wa0 = (const float*)d_in[25]; const float* ba0 = (const float*)d_in[26];
  const float* Wa1 = (const float*)d_in[27]; const float* ba1 = (const float*)d_in[28];
  const float* Wn3 = (const float*)d_in[29]; const float* bn3 = (const float*)d_in[30];
  unsigned short* WT = (unsigned short*)d_ws;
  float* out = (float*)d_out;

  prep_weights<<<WT_TOTAL / 256, 256, 0, stream>>>(Wld, Wrd, Wfd, Wc1, Wc2, Wc3, Wcd,
                                                   Wcn, Wnd, Wn1, Wn2, Wa0, Wa1, Wn3, WT);
  fused_vae<<<NN / BM, 512, 0, stream>>>(z, cind, Emb, bld, brd, bfd, bc1, bc2, bc3,
                                         bcd, bcn, bnd, bn1, bn2, ba0, ba1, bn3, WT, out);
}